// Round 2
// 597.037 us; speedup vs baseline: 1.0072x; 1.0072x over previous
//
#include <hip/hip_runtime.h>
#include <math.h>

#define S_IN   22
#define S_DIM  256
#define PE_D   64
#define L_TOT  1024
// region starts (cumsum of [1,400,300,15,110,50,100,48])
// 0:[0,1) collapse, 1:hd[1,401), 2:mhc[401,701), 3:pep[701,716),
// 4:lv[716,826), 5:lj[826,876), 6:hv[876,976), 7:hj[976,1024)

typedef float f4 __attribute__((ext_vector_type(4)));

__global__ __launch_bounds__(256) void s_out_kernel(
    const float* __restrict__ hd,  const int* __restrict__ hd_idx,
    const float* __restrict__ mhc, const int* __restrict__ mhc_idx,
    const float* __restrict__ pep, const int* __restrict__ pep_idx,
    const float* __restrict__ lv,  const int* __restrict__ lv_idx,
    const float* __restrict__ lj,  const int* __restrict__ lj_idx,
    const float* __restrict__ hv,  const int* __restrict__ hv_idx,
    const float* __restrict__ hj,  const int* __restrict__ hj_idx,
    const int*  __restrict__ mask,
    const float* __restrict__ W_seq, const float* __restrict__ b_seq,
    const float* __restrict__ W_pos, const float* __restrict__ b_pos,
    const float* __restrict__ collapse_token,
    const float* __restrict__ collapse_weight,
    const float* __restrict__ rw_hd, const float* __restrict__ rw_mhc,
    const float* __restrict__ rw_pep, const float* __restrict__ rw_lv,
    const float* __restrict__ rw_lj, const float* __restrict__ rw_hv,
    const float* __restrict__ rw_hj,
    float* __restrict__ out)
{
    const int row = blockIdx.x;
    const int c   = threadIdx.x;   // 0..255, one output column each

    if (row == 0) {
        out[c] = collapse_weight[0] * collapse_token[c];
        return;
    }

    // block-uniform region select
    const float* aa; const int* idx; const float* rw; int start; int isHd = 0;
    if      (row < 401) { aa = hd;  idx = hd_idx;  rw = rw_hd;  start = 1;   isHd = 1; }
    else if (row < 701) { aa = mhc; idx = mhc_idx; rw = rw_mhc; start = 401; }
    else if (row < 716) { aa = pep; idx = pep_idx; rw = rw_pep; start = 701; }
    else if (row < 826) { aa = lv;  idx = lv_idx;  rw = rw_lv;  start = 716; }
    else if (row < 876) { aa = lj;  idx = lj_idx;  rw = rw_lj;  start = 826; }
    else if (row < 976) { aa = hv;  idx = hv_idx;  rw = rw_hv;  start = 876; }
    else                { aa = hj;  idx = hj_idx;  rw = rw_hj;  start = 976; }
    const int r = row - start;

    __shared__ float sa[S_IN];
    __shared__ float pe[PE_D];

    if (c < S_IN) {
        float v = aa[r * S_IN + c];
        if (isHd && mask[r] == 1) v = 0.0f;
        sa[c] = v;
    }
    if (c >= 64 && c < 64 + PE_D) {
        const int d = c - 64;
        const float p = (float)idx[r];
        // 10000^(-d/64) = exp(-(d/64)*ln(10000))
        const float inv_freq = expf(-((float)d / (float)PE_D) * 9.210340371976184f);
        const float ang = p * inv_freq;
        pe[d] = (d & 1) ? cosf(ang) : sinf(ang);
    }
    __syncthreads();

    float acc_s = b_seq[c];
    #pragma unroll
    for (int f = 0; f < S_IN; ++f)
        acc_s = fmaf(sa[f], W_seq[f * S_DIM + c], acc_s);

    float acc_p = b_pos[c];
    #pragma unroll
    for (int d = 0; d < PE_D; ++d)
        acc_p = fmaf(pe[d], W_pos[d * S_DIM + c], acc_p);

    out[row * S_DIM + c] = rw[0] * acc_s + rw[1] * acc_p;
}

// z: (1024,1024,128) fp32 = 512 MiB of writes, only 26 distinct 512-B rows.
// For a fixed row i, pid(j) is piecewise-constant in j: at most 12 segments
// (collapse column, hd-diagonal splits, 6 condition regions). Build the
// segment list once per block (block-uniform, thread 0 -> LDS), hoist the
// 16-B pattern chunk into a register per segment, and make the inner loop
// pure address-increment + nontemporal store.
// 4 blocks per row; each block owns a 256-column window. A wave writes 2
// consecutive j-rows = contiguous 1 KiB (16 full 64-B lines).
__global__ __launch_bounds__(256) void z_kernel(
    const float* __restrict__ W_p1, const float* __restrict__ b_p1,
    const float* __restrict__ W_p2, const float* __restrict__ b_p2,
    f4* __restrict__ z)
{
    __shared__ alignas(16) float table[26 * 128];
    __shared__ int seg_s[16], seg_e[16], seg_p[16];
    __shared__ int ns_sh;

    for (int t = threadIdx.x; t < 26 * 128; t += 256) {
        const int p = t >> 7, k = t & 127;
        float v;
        if (k < 64) v = W_p1[(p >> 2) * 64 + k]       + b_p1[k];
        else        v = W_p2[(p & 3) * 64 + (k - 64)] + b_p2[k - 64];
        table[t] = v;
    }

    const int i  = blockIdx.x >> 2;          // row
    const int j0 = (blockIdx.x & 3) << 8;    // column window [j0, j0+256)
    const int j1 = j0 + 256;

    if (threadIdx.x == 0) {
        int ns = 0;
        auto add = [&](int s, int e, int p) {
            if (s < e) { seg_s[ns] = s; seg_e[ns] = e; seg_p[ns] = p; ++ns; }
        };
        const int ri = (i >= 1) + (i >= 401) + (i >= 701) + (i >= 716) +
                       (i >= 826) + (i >= 876) + (i >= 976);
        if (ri == 0) {
            add(0, 1, 0);                     // (collapse, collapse)
            add(1, L_TOT, 1);                 // collapse row
        } else {
            const int rs[9] = {0, 1, 401, 701, 716, 826, 876, 976, 1024};
            add(0, 1, 1);                     // collapse column
            #pragma unroll
            for (int rj = 1; rj < 8; ++rj) {
                const int s = rs[rj], e = rs[rj + 1];
                if (ri == 1 && rj == 1) {
                    // hd-hd: di>1 -> 3, di==1 -> 2, di==0 -> 0
                    add(1, i - 1, 3);                           // [1, i-1)
                    add((i - 1 > 1 ? i - 1 : 1), i, 2);         // {i-1}
                    add(i, (i + 1 < 401 ? i + 1 : 401), 0);     // {i}
                    add(i + 1, (i + 2 < 401 ? i + 2 : 401), 2); // {i+1}
                    add(i + 2, 401, 3);                         // [i+2, 401)
                } else if (ri == 1 || rj == 1) {
                    add(s, e, 4);                               // hd vs cond
                } else if (ri == rj) {
                    add(s, e, 3 + ri);                          // same cond region
                } else {                                        // cross cond regions
                    const int m1 = ((ri < rj) ? ri : rj) - 2;
                    const int m2 = ((ri > rj) ? ri : rj) - 2;
                    add(s, e, 11 + m1 * 6 - (m1 * (m1 + 1)) / 2 + (m2 - m1 - 1));
                }
            }
        }
        ns_sh = ns;
    }
    __syncthreads();

    const int ns     = ns_sh;
    const int koff   = threadIdx.x & 31;     // float4 index within a 128-row
    const int lane_j = threadIdx.x >> 5;     // 8 j-rows per iteration
    f4* const zrow = z + ((size_t)i << 15);  // 32768 float4 per row

    for (int s = 0; s < ns; ++s) {
        const int ss = seg_s[s], ee = seg_e[s];
        const int js = ss > j0 ? ss : j0;
        const int je = ee < j1 ? ee : j1;
        if (js >= je) continue;
        const f4 v = *reinterpret_cast<const f4*>(&table[(seg_p[s] << 7) + (koff << 2)]);
        for (int j = js + lane_j; j < je; j += 8) {
            __builtin_nontemporal_store(v, &zrow[(j << 5) + koff]);
        }
    }
}

extern "C" void kernel_launch(void* const* d_in, const int* in_sizes, int n_in,
                              void* d_out, int out_size, void* d_ws, size_t ws_size,
                              hipStream_t stream) {
    const float* hd       = (const float*)d_in[0];
    const int*   hd_idx   = (const int*)  d_in[1];
    const float* mhc      = (const float*)d_in[2];
    const int*   mhc_idx  = (const int*)  d_in[3];
    const float* pep      = (const float*)d_in[4];
    const int*   pep_idx  = (const int*)  d_in[5];
    const float* lv       = (const float*)d_in[6];
    const int*   lv_idx   = (const int*)  d_in[7];
    const float* lj       = (const float*)d_in[8];
    const int*   lj_idx   = (const int*)  d_in[9];
    const float* hv       = (const float*)d_in[10];
    const int*   hv_idx   = (const int*)  d_in[11];
    const float* hj       = (const float*)d_in[12];
    const int*   hj_idx   = (const int*)  d_in[13];
    const int*   mask     = (const int*)  d_in[14];
    const float* W_seq    = (const float*)d_in[15];
    const float* b_seq    = (const float*)d_in[16];
    const float* W_pos    = (const float*)d_in[17];
    const float* b_pos    = (const float*)d_in[18];
    const float* W_p1     = (const float*)d_in[19];
    const float* b_p1     = (const float*)d_in[20];
    const float* W_p2     = (const float*)d_in[21];
    const float* b_p2     = (const float*)d_in[22];
    const float* collapse_token  = (const float*)d_in[23];
    const float* collapse_weight = (const float*)d_in[24];
    const float* rw_hd    = (const float*)d_in[25];
    const float* rw_mhc   = (const float*)d_in[26];
    const float* rw_pep   = (const float*)d_in[27];
    const float* rw_lv    = (const float*)d_in[28];
    const float* rw_lj    = (const float*)d_in[29];
    const float* rw_hv    = (const float*)d_in[30];
    const float* rw_hj    = (const float*)d_in[31];

    float* out = (float*)d_out;

    s_out_kernel<<<L_TOT, 256, 0, stream>>>(
        hd, hd_idx, mhc, mhc_idx, pep, pep_idx, lv, lv_idx, lj, lj_idx,
        hv, hv_idx, hj, hj_idx, mask, W_seq, b_seq, W_pos, b_pos,
        collapse_token, collapse_weight,
        rw_hd, rw_mhc, rw_pep, rw_lv, rw_lj, rw_hv, rw_hj, out);

    z_kernel<<<4096, 256, 0, stream>>>(
        W_p1, b_p1, W_p2, b_p2,
        reinterpret_cast<f4*>(out + L_TOT * S_DIM));
}